// Round 4
// baseline (100.567 us; speedup 1.0000x reference)
//
#include <hip/hip_runtime.h>
#include <math.h>

#define N 1024
#define H 128
#define CLIPV 10.0f

#define TI 64              // i rows per tile
#define TJ 32              // j rows per tile
#define LDSP 132           // padded row stride: 132 % 32 = 4 -> 4-bank rotation/row
#define GRID_I (N / TI)    // 16
#define GRID_J (N / TJ)    // 32
#define NBLK (GRID_I * GRID_J)   // 512 pair-blocks

// ---------------------------------------------------------------------------
// Kernel A (element-parallel): one thread per (row,h) computes
//   A[row][h]  = dot(z_c[row], w1[:,h][:128])
//   Cb[row][h] = dot(z_d[row], w1[:,h][128:]) + b1[h]
// 131072 threads = 256 blocks x 512. Also zeroes acc/counter for k_pair
// (visible at kernel boundary).
// ---------------------------------------------------------------------------
__global__ __launch_bounds__(512) void k_gemm(const float* __restrict__ z_c,
                                              const float* __restrict__ z_d,
                                              const float* __restrict__ w1,
                                              const float* __restrict__ b1,
                                              float* __restrict__ A,
                                              float* __restrict__ Cb,
                                              double* __restrict__ acc,
                                              int* __restrict__ counter) {
    const int tid = threadIdx.x;
    if (blockIdx.x == 0 && tid == 0) {
        acc[0] = 0.0; acc[1] = 0.0; *counter = 0;
    }
    const int gid = blockIdx.x * 512 + tid;
    const int row = gid >> 7;          // 0..1023
    const int h   = gid & 127;
    const float* __restrict__ zc = z_c + row * H;
    const float* __restrict__ zd = z_d + row * H;

    float a = 0.f, c = 0.f;
    #pragma unroll 8
    for (int k = 0; k < H; ++k) {
        a = fmaf(zc[k], w1[k * H + h],       a);   // wave-uniform z, coalesced w
        c = fmaf(zd[k], w1[(H + k) * H + h], c);
    }
    A[row * H + h]  = a;
    Cb[row * H + h] = c + b1[h];
}

// ---------------------------------------------------------------------------
// Kernel B: pairwise T1 = sum_h relu(A[j][h]+Cb[i][h])*w2[h] + b2
// 64(i) x 32(j) tile per block, 512 threads = 4 h-quarters x 128 compute
// threads (relu is per-h; h-sum linear -> split legal). 512 blocks, 51 KB LDS
// -> 2 blocks/CU = 16 waves/CU. Per-block f64 atomics + counter; last block
// finalizes the scalar (no separate k_final).
// ---------------------------------------------------------------------------
__global__ __launch_bounds__(512, 1) void k_pair(const float* __restrict__ A,
                                                 const float* __restrict__ Cb,
                                                 const float* __restrict__ w2,
                                                 const float* __restrict__ b2p,
                                                 double* __restrict__ acc,
                                                 int* __restrict__ counter,
                                                 float* __restrict__ out) {
    __shared__ float Ash[TJ][LDSP];    // 32 j rows   (4224 floats)
    __shared__ float Csh[TI][LDSP];    // 64 i rows   (8448 floats)
    __shared__ float w2s[H];
    __shared__ float red[4];

    const int tid = threadIdx.x;
    const int i0 = blockIdx.x * TI;
    const int j0 = blockIdx.y * TJ;

    // ---- staging: 512 threads; 96 rows x 32 float4 cols ----
    {
        const int c4 = (tid & 31) * 4;
        const int r  = tid >> 5;       // 0..15
        *(float4*)&Csh[r     ][c4] = *(const float4*)&Cb[(i0 + r     ) * H + c4];
        *(float4*)&Csh[r + 16][c4] = *(const float4*)&Cb[(i0 + r + 16) * H + c4];
        *(float4*)&Csh[r + 32][c4] = *(const float4*)&Cb[(i0 + r + 32) * H + c4];
        *(float4*)&Csh[r + 48][c4] = *(const float4*)&Cb[(i0 + r + 48) * H + c4];
        *(float4*)&Ash[r     ][c4] = *(const float4*)&A [(j0 + r     ) * H + c4];
        *(float4*)&Ash[r + 16][c4] = *(const float4*)&A [(j0 + r + 16) * H + c4];
        if (tid < 32) *(float4*)&w2s[tid * 4] = *(const float4*)&w2[tid * 4];
    }
    __syncthreads();

    const int t128 = tid & 127;
    const int hh = tid >> 7;           // h-quarter 0..3 (wave-uniform)
    const int tj = t128 & 7;           // j group (8)
    const int ti = t128 >> 3;          // i group (16)

    float s[4][4] = {{0.f,0.f,0.f,0.f},{0.f,0.f,0.f,0.f},
                     {0.f,0.f,0.f,0.f},{0.f,0.f,0.f,0.f}};

    #pragma unroll 4
    for (int h4i = 0; h4i < 8; ++h4i) {
        const int h4 = hh * 8 + h4i;
        const float4 w4 = *(const float4*)&w2s[h4 * 4];
        float4 cf[4], af[4];
        #pragma unroll
        for (int d = 0; d < 4; ++d) {
            cf[d] = *(const float4*)&Csh[ti + d * 16][h4 * 4];
            af[d] = *(const float4*)&Ash[tj + d * 8 ][h4 * 4];
        }
        #pragma unroll
        for (int q = 0; q < 4; ++q) {
            const float wv = ((const float*)&w4)[q];
            #pragma unroll
            for (int di = 0; di < 4; ++di) {
                const float cv = ((const float*)&cf[di])[q];
                #pragma unroll
                for (int dj = 0; dj < 4; ++dj) {
                    const float t = fmaxf(cv + ((const float*)&af[dj])[q], 0.f);
                    s[di][dj] = fmaf(t, wv, s[di][dj]);
                }
            }
        }
    }

    // ---- combine 4 h-quarters via LDS scratch (stride 17: <=2-way, free) ---
    __syncthreads();                       // compute done; safe to overwrite
    float* scr1 = &Ash[0][0];              // 2192 floats <= 4224
    float* scr2 = &Csh[0][0];              // regions in Csh: 2*2192 <= 8448
    float* scr3 = &Csh[0][0] + 2192;
    if (hh != 0) {
        float* dst = (hh == 1) ? scr1 : (hh == 2) ? scr2 : scr3;
        #pragma unroll
        for (int di = 0; di < 4; ++di) {
            float4 v4;
            v4.x = s[di][0]; v4.y = s[di][1]; v4.z = s[di][2]; v4.w = s[di][3];
            *(float4*)&dst[t128 * 17 + di * 4] = v4;
        }
    }
    __syncthreads();

    float diag = 0.f, sume = 0.f;
    if (hh == 0) {
        const float b2 = b2p[0];
        #pragma unroll
        for (int di = 0; di < 4; ++di) {
            const float4 p1 = *(const float4*)&scr1[t128 * 17 + di * 4];
            const float4 p2 = *(const float4*)&scr2[t128 * 17 + di * 4];
            const float4 p3 = *(const float4*)&scr3[t128 * 17 + di * 4];
            #pragma unroll
            for (int dj = 0; dj < 4; ++dj) {
                const float v = s[di][dj] + ((const float*)&p1)[dj]
                              + ((const float*)&p2)[dj] + ((const float*)&p3)[dj] + b2;
                const int i = i0 + ti + di * 16;
                const int j = j0 + tj + dj * 8;
                if (i == j) {
                    diag += v;
                } else {
                    const float vc = fminf(fmaxf(v, -CLIPV), CLIPV);
                    sume += __expf(vc - CLIPV);
                }
            }
        }
    }

    // ---- reduce: data lives in waves 0,1 only ----
    #pragma unroll
    for (int off = 32; off; off >>= 1) {
        diag += __shfl_down(diag, off);
        sume += __shfl_down(sume, off);
    }
    if (tid == 0)  { red[0] = diag; red[2] = sume; }
    if (tid == 64) { red[1] = diag; red[3] = sume; }
    __syncthreads();
    if (tid == 0) {
        atomicAdd(&acc[0], (double)(red[0] + red[1]));
        atomicAdd(&acc[1], (double)(red[2] + red[3]));
        __threadfence();
        const int old = atomicAdd(counter, 1);
        if (old == NBLK - 1) {              // last block: finalize
            const double dt = atomicAdd(&acc[0], 0.0);   // coherent read
            const double et = atomicAdd(&acc[1], 0.0);
            const double T0  = dt / (double)N;
            const double lme = log(et) + (double)CLIPV
                             - log((double)N * ((double)N - 1.0));
            out[0] = (float)(T0 - lme);
        }
    }
}

extern "C" void kernel_launch(void* const* d_in, const int* in_sizes, int n_in,
                              void* d_out, int out_size, void* d_ws, size_t ws_size,
                              hipStream_t stream) {
    const float* z_c = (const float*)d_in[0];
    const float* z_d = (const float*)d_in[1];
    const float* w1  = (const float*)d_in[2];
    const float* b1  = (const float*)d_in[3];
    const float* w2  = (const float*)d_in[4];
    const float* b2  = (const float*)d_in[5];

    float*  A       = (float*)d_ws;                    // N*H
    float*  Cb      = A + N * H;                       // N*H
    double* acc     = (double*)(Cb + N * H);           // 2 doubles (8B-aligned)
    int*    counter = (int*)(acc + 2);

    k_gemm<<<dim3(256), 512, 0, stream>>>(z_c, z_d, w1, b1, A, Cb, acc, counter);
    k_pair<<<dim3(GRID_I, GRID_J), 512, 0, stream>>>(A, Cb, w2, b2, acc, counter,
                                                     (float*)d_out);
}

// Round 5
// 92.448 us; speedup vs baseline: 1.0878x; 1.0878x over previous
//
#include <hip/hip_runtime.h>
#include <math.h>

#define N 1024
#define H 128
#define CLIPV 10.0f

#define TI 64
#define TJ 64
#define LDSP 132           // padded row stride: 132 % 32 = 4 -> 4-bank rotation/row
#define NBLK ((N / TI) * (N / TJ))   // 256 pair-blocks

// ---------------------------------------------------------------------------
// Kernel A (R3-proven): A[j][h]  = z_c @ w1[:128]
//                       Cb[i][h] = z_d @ w1[128:] + b1
// grid (N/8, 2), block 256. 8 rows staged in LDS; w loads coalesced.
// Block (0,0) also zeroes acc/counter for k_pair (kernel-boundary visible).
// ---------------------------------------------------------------------------
__global__ __launch_bounds__(256) void k_gemm(const float* __restrict__ z_c,
                                              const float* __restrict__ z_d,
                                              const float* __restrict__ w1,
                                              const float* __restrict__ b1,
                                              float* __restrict__ A,
                                              float* __restrict__ Cb,
                                              double* __restrict__ acc,
                                              int* __restrict__ counter) {
    const int which = blockIdx.y;            // 0 -> A, 1 -> Cb
    const int n0 = blockIdx.x * 8;
    const int tid = threadIdx.x;
    if (blockIdx.x == 0 && which == 0 && tid == 0) {
        acc[0] = 0.0; acc[1] = 0.0; *counter = 0;
    }
    const float* __restrict__ z = which ? z_d : z_c;
    const float* __restrict__ w = w1 + which * (H * H);

    __shared__ float zs[8][H];
    {
        const int c4 = (tid & 31) * 4;
        const int r  = tid >> 5;             // 0..7
        *(float4*)&zs[r][c4] = *(const float4*)&z[(n0 + r) * H + c4];
    }
    __syncthreads();

    const int h = tid & 127;
    const int g = tid >> 7;                  // row-group 0/1 (rows g*4..g*4+3)

    float a0 = 0.f, a1 = 0.f, a2 = 0.f, a3 = 0.f;
    #pragma unroll 8
    for (int k = 0; k < H; ++k) {
        const float wv = w[k * H + h];
        a0 = fmaf(zs[g * 4 + 0][k], wv, a0);
        a1 = fmaf(zs[g * 4 + 1][k], wv, a1);
        a2 = fmaf(zs[g * 4 + 2][k], wv, a2);
        a3 = fmaf(zs[g * 4 + 3][k], wv, a3);
    }
    const float bias = which ? b1[h] : 0.0f;
    float* __restrict__ dst = which ? Cb : A;
    dst[(n0 + g * 4 + 0) * H + h] = a0 + bias;
    dst[(n0 + g * 4 + 1) * H + h] = a1 + bias;
    dst[(n0 + g * 4 + 2) * H + h] = a2 + bias;
    dst[(n0 + g * 4 + 3) * H + h] = a3 + bias;
}

// ---------------------------------------------------------------------------
// Kernel B (R3 structure): 64x64 tile, 512 threads = 2 h-halves x 256.
// Delta vs R3: __launch_bounds__(512,4) caps VGPR at 128 -> 2 blocks/CU
// (LDS 68KB -> 136KB for 2 blocks <= 160KB). Finalize merged via f64
// atomics + device counter; last block writes the scalar.
// ---------------------------------------------------------------------------
__global__ __launch_bounds__(512, 4) void k_pair(const float* __restrict__ A,
                                                 const float* __restrict__ Cb,
                                                 const float* __restrict__ w2,
                                                 const float* __restrict__ b2p,
                                                 double* __restrict__ acc,
                                                 int* __restrict__ counter,
                                                 float* __restrict__ out) {
    __shared__ float Ash[TJ][LDSP];
    __shared__ float Csh[TI][LDSP];
    __shared__ float w2s[H];
    __shared__ float red[16];

    const int tid = threadIdx.x;
    const int i0 = blockIdx.x * TI;
    const int j0 = blockIdx.y * TJ;

    // ---- staging: 512 threads, 128 rows (64 A + 64 C) x 32 float4 cols ----
    {
        const int c4 = (tid & 31) * 4;
        const int r  = tid >> 5;             // 0..15
        #pragma unroll
        for (int rr = 0; rr < 4; ++rr) {
            const int row = r + rr * 16;     // 0..63
            *(float4*)&Ash[row][c4] = *(const float4*)&A[(j0 + row) * H + c4];
            *(float4*)&Csh[row][c4] = *(const float4*)&Cb[(i0 + row) * H + c4];
        }
        if (tid < 32) *(float4*)&w2s[tid * 4] = *(const float4*)&w2[tid * 4];
    }
    __syncthreads();

    const int t256 = tid & 255;
    const int tj = t256 & 15;                // j group (16)
    const int ti = t256 >> 4;                // i group (16)
    const int hh = tid >> 8;                 // h-half 0/1

    float s[4][4] = {{0.f,0.f,0.f,0.f},{0.f,0.f,0.f,0.f},
                     {0.f,0.f,0.f,0.f},{0.f,0.f,0.f,0.f}};

    const int h4base = hh * 16;
    #pragma unroll 4
    for (int h4i = 0; h4i < 16; ++h4i) {
        const int h4 = h4base + h4i;
        const float4 w4 = *(const float4*)&w2s[h4 * 4];
        float4 cf[4], af[4];
        #pragma unroll
        for (int d = 0; d < 4; ++d) {
            cf[d] = *(const float4*)&Csh[ti + d * 16][h4 * 4];
            af[d] = *(const float4*)&Ash[tj + d * 16][h4 * 4];
        }
        #pragma unroll
        for (int q = 0; q < 4; ++q) {
            const float wv = ((const float*)&w4)[q];
            #pragma unroll
            for (int di = 0; di < 4; ++di) {
                const float cv = ((const float*)&cf[di])[q];
                #pragma unroll
                for (int dj = 0; dj < 4; ++dj) {
                    const float t = fmaxf(cv + ((const float*)&af[dj])[q], 0.f);
                    s[di][dj] = fmaf(t, wv, s[di][dj]);
                }
            }
        }
    }

    // ---- combine h-halves (reuse Ash as scratch; stride 20 -> <=2-way) ----
    float* comb = &Ash[0][0];                // 256*20 = 5120 <= 64*132
    __syncthreads();
    if (hh == 1) {
        #pragma unroll
        for (int di = 0; di < 4; ++di) {
            float4 v4;
            v4.x = s[di][0]; v4.y = s[di][1]; v4.z = s[di][2]; v4.w = s[di][3];
            *(float4*)&comb[t256 * 20 + di * 4] = v4;
        }
    }
    __syncthreads();

    float diag = 0.f, sume = 0.f;
    if (hh == 0) {
        const float b2 = b2p[0];
        #pragma unroll
        for (int di = 0; di < 4; ++di) {
            #pragma unroll
            for (int dj = 0; dj < 4; ++dj) {
                const float v = s[di][dj] + comb[t256 * 20 + di * 4 + dj] + b2;
                const int i = i0 + ti + di * 16;
                const int j = j0 + tj + dj * 16;
                if (i == j) {
                    diag += v;
                } else {
                    const float vc = fminf(fmaxf(v, -CLIPV), CLIPV);
                    sume += __expf(vc - CLIPV);
                }
            }
        }
    }

    // ---- block reduction: wave shuffle, LDS across 8 waves, atomics ----
    #pragma unroll
    for (int off = 32; off; off >>= 1) {
        diag += __shfl_down(diag, off);
        sume += __shfl_down(sume, off);
    }
    if ((tid & 63) == 0) { red[tid >> 6] = diag; red[8 + (tid >> 6)] = sume; }
    __syncthreads();
    if (tid == 0) {
        float d = 0.f, e = 0.f;
        #pragma unroll
        for (int k = 0; k < 8; ++k) { d += red[k]; e += red[8 + k]; }
        atomicAdd(&acc[0], (double)d);
        atomicAdd(&acc[1], (double)e);
        __threadfence();
        const int old = atomicAdd(counter, 1);
        if (old == NBLK - 1) {               // last block finalizes
            const double dt = atomicAdd(&acc[0], 0.0);   // coherent read
            const double et = atomicAdd(&acc[1], 0.0);
            const double T0  = dt / (double)N;
            const double lme = log(et) + (double)CLIPV
                             - log((double)N * ((double)N - 1.0));
            out[0] = (float)(T0 - lme);
        }
    }
}

extern "C" void kernel_launch(void* const* d_in, const int* in_sizes, int n_in,
                              void* d_out, int out_size, void* d_ws, size_t ws_size,
                              hipStream_t stream) {
    const float* z_c = (const float*)d_in[0];
    const float* z_d = (const float*)d_in[1];
    const float* w1  = (const float*)d_in[2];
    const float* b1  = (const float*)d_in[3];
    const float* w2  = (const float*)d_in[4];
    const float* b2  = (const float*)d_in[5];

    float*  A       = (float*)d_ws;                    // N*H
    float*  Cb      = A + N * H;                       // N*H
    double* acc     = (double*)(Cb + N * H);           // 2 doubles
    int*    counter = (int*)(acc + 2);

    k_gemm<<<dim3(N / 8, 2), 256, 0, stream>>>(z_c, z_d, w1, b1, A, Cb,
                                               acc, counter);
    k_pair<<<dim3(N / TI, N / TJ), 512, 0, stream>>>(A, Cb, w2, b2,
                                                     acc, counter,
                                                     (float*)d_out);
}